// Round 1
// baseline (21.888 us; speedup 1.0000x reference)
//
#include <hip/hip_runtime.h>
#include <math.h>

#define B_TOT 16384
#define F_SP  26
#define F_DN  13
#define VOCAB 100000
#define EMB   16

// 8 threads per sample: g = tid&7, dc = g&3 (dim chunk of 4), fh = g>>2 (feature half).
// Block 256 -> 32 samples/block, grid 512 -> 2 blocks/CU on 256 CUs.
__global__ __launch_bounds__(256) void fm_mtl_kernel(
    const int*   __restrict__ sparse,    // [B, 26]
    const float* __restrict__ dense,     // [B, 13]
    const float* __restrict__ ldW,       // [13, 1]
    const float* __restrict__ ldB,       // [1]
    const float* __restrict__ lin_emb,   // [26, 100000, 1]
    const float* __restrict__ fm_emb,    // [26, 100000, 16]
    const float* __restrict__ fW,        // [1,1]
    const float* __restrict__ fB,        // [1]
    const float* __restrict__ lW,        // [1,1]
    const float* __restrict__ lB,        // [1]
    float*       __restrict__ out)       // [B, 2]
{
    __shared__ int s_idx[32 * F_SP];
    const int tid = threadIdx.x;
    const int block_base = blockIdx.x * 32;   // first sample of this block

    // Stage the 32 samples' indices (832 ints) coalesced into LDS.
    for (int i = tid; i < 32 * F_SP; i += 256)
        s_idx[i] = sparse[block_base * F_SP + i];
    __syncthreads();

    const int sloc = tid >> 3;   // sample within block
    const int g    = tid & 7;
    const int dc   = g & 3;      // which 4 of the 16 emb dims
    const int fh   = g >> 2;     // which half of the 26 features
    const int b    = block_base + sloc;

    const int* idx = &s_idx[sloc * F_SP];

    float4 s = make_float4(0.f, 0.f, 0.f, 0.f);
    float ssq = 0.f;
    const int f0 = fh * 13;
    #pragma unroll
    for (int k = 0; k < 13; ++k) {
        const int f = f0 + k;
        const int v = idx[f];
        const float4 e = *reinterpret_cast<const float4*>(
            &fm_emb[((size_t)f * VOCAB + (size_t)v) * EMB + dc * 4]);
        s.x += e.x; s.y += e.y; s.z += e.z; s.w += e.w;
        ssq += e.x * e.x + e.y * e.y + e.z * e.z + e.w * e.w;
    }

    // First-order terms: 2 of the 8 lanes (dc==0) each handle 13 linear_emb
    // gathers; lane g==0 additionally does the dense dot.
    float lin = 0.f;
    if (dc == 0) {
        #pragma unroll
        for (int k = 0; k < 13; ++k) {
            const int f = f0 + k;
            const int v = idx[f];
            lin += lin_emb[(size_t)f * VOCAB + (size_t)v];
        }
        if (fh == 0) {
            float ld = ldB[0];
            #pragma unroll
            for (int j = 0; j < F_DN; ++j)
                ld += dense[b * F_DN + j] * ldW[j];
            lin += ld;
        }
    }

    // Combine the per-half partial sums of the embedding vector (lane ^ 4).
    s.x += __shfl_xor(s.x, 4);
    s.y += __shfl_xor(s.y, 4);
    s.z += __shfl_xor(s.z, 4);
    s.w += __shfl_xor(s.w, 4);

    // Per-lane contribution to logits:
    //   sum over 8 lanes of 0.25*p2 = 0.5 * sum_e s_e^2   (p2 duplicated across halves)
    //   sum over 8 lanes of 0.5*ssq = 0.5 * sum_f sum_e e^2 (disjoint partition)
    //   sum over 8 lanes of lin     = full first-order
    const float p2 = s.x * s.x + s.y * s.y + s.z * s.z + s.w * s.w;
    float r = 0.25f * p2 - 0.5f * ssq + lin;
    r += __shfl_xor(r, 1);
    r += __shfl_xor(r, 2);
    r += __shfl_xor(r, 4);

    if (g == 0) {
        const float finish = 1.f / (1.f + expf(-(r * fW[0] + fB[0])));
        const float like   = 1.f / (1.f + expf(-(r * lW[0] + lB[0])));
        *reinterpret_cast<float2*>(&out[b * 2]) = make_float2(finish, like);
    }
}

extern "C" void kernel_launch(void* const* d_in, const int* in_sizes, int n_in,
                              void* d_out, int out_size, void* d_ws, size_t ws_size,
                              hipStream_t stream) {
    const int*   sparse  = (const int*)  d_in[0];
    const float* dense   = (const float*)d_in[1];
    const float* ldW     = (const float*)d_in[2];
    const float* ldB     = (const float*)d_in[3];
    const float* lin_emb = (const float*)d_in[4];
    const float* fm_emb  = (const float*)d_in[5];
    const float* fW      = (const float*)d_in[6];
    const float* fB      = (const float*)d_in[7];
    const float* lW      = (const float*)d_in[8];
    const float* lB      = (const float*)d_in[9];
    float* out = (float*)d_out;

    dim3 grid(B_TOT / 32);   // 512
    dim3 block(256);
    fm_mtl_kernel<<<grid, block, 0, stream>>>(
        sparse, dense, ldW, ldB, lin_emb, fm_emb, fW, fB, lW, lB, out);
}

// Round 2
// 20.642 us; speedup vs baseline: 1.0604x; 1.0604x over previous
//
#include <hip/hip_runtime.h>
#include <math.h>

#define B_TOT 16384
#define F_SP  26
#define F_DN  13
#define VOCAB 100000
#define EMB   16

// 16 threads per sample: g = tid&15, d = g&7 (float2 dim chunk), fh = g>>3
// (feature half). Block 256 -> 16 samples/block, grid 1024 -> 4 blocks/CU,
// 16 waves/CU (4/SIMD) on 256 CUs.
__global__ __launch_bounds__(256) void fm_mtl_kernel(
    const int*   __restrict__ sparse,    // [B, 26]
    const float* __restrict__ dense,     // [B, 13]
    const float* __restrict__ ldW,       // [13, 1]
    const float* __restrict__ ldB,       // [1]
    const float* __restrict__ lin_emb,   // [26, 100000, 1]
    const float* __restrict__ fm_emb,    // [26, 100000, 16]
    const float* __restrict__ fW,        // [1,1]
    const float* __restrict__ fB,        // [1]
    const float* __restrict__ lW,        // [1,1]
    const float* __restrict__ lB,        // [1]
    float*       __restrict__ out)       // [B, 2]
{
    __shared__ int s_idx[16 * F_SP];
    const int tid = threadIdx.x;
    const int block_base = blockIdx.x * 16;   // first sample of this block

    // Stage the 16 samples' indices (416 ints) coalesced into LDS.
    for (int i = tid; i < 16 * F_SP; i += 256)
        s_idx[i] = sparse[block_base * F_SP + i];
    __syncthreads();

    const int sloc = tid >> 4;   // sample within block
    const int g    = tid & 15;
    const int d    = g & 7;      // which float2 of the 16 emb dims
    const int fh   = g >> 3;     // which half of the 26 features
    const int b    = block_base + sloc;

    const int* idx = &s_idx[sloc * F_SP];

    // --- first-order gathers, issued early so they overlap the fm gathers ---
    // Lane g handles lin feature g (all 16 lanes) and g+16 (lanes 0..9).
    float lin = lin_emb[(size_t)g * VOCAB + (size_t)idx[g]];
    if (g < 10)
        lin += lin_emb[(size_t)(g + 16) * VOCAB + (size_t)idx[g + 16]];
    // Dense dot spread over lanes 0..12 (coalesced 13-float read per sample).
    if (g < F_DN)
        lin += dense[b * F_DN + g] * ldW[g];
    if (g == 0)
        lin += ldB[0];

    // --- second-order: 13 independent float2 gathers per thread ---
    float2 s = make_float2(0.f, 0.f);
    float ssq = 0.f;
    const int f0 = fh * 13;
    #pragma unroll
    for (int k = 0; k < 13; ++k) {
        const int f = f0 + k;
        const int v = idx[f];
        const float2 e = *reinterpret_cast<const float2*>(
            &fm_emb[((size_t)f * VOCAB + (size_t)v) * EMB + d * 2]);
        s.x += e.x; s.y += e.y;
        ssq += e.x * e.x + e.y * e.y;
    }

    // Combine the two feature-halves of the summed vector (lane ^ 8).
    s.x += __shfl_xor(s.x, 8);
    s.y += __shfl_xor(s.y, 8);

    // Per-lane contribution; summed over the aligned 16-lane group:
    //   0.25*p2 appears twice per dim-lane  -> 0.5 * sum_e s_e^2
    //   0.5*ssq over disjoint (f,e) ranges  -> 0.5 * sum_f sum_e e^2
    //   lin/dense terms disjoint            -> full first-order
    const float p2 = s.x * s.x + s.y * s.y;
    float r = 0.25f * p2 - 0.5f * ssq + lin;
    r += __shfl_xor(r, 1);
    r += __shfl_xor(r, 2);
    r += __shfl_xor(r, 4);
    r += __shfl_xor(r, 8);

    if (g == 0) {
        const float finish = 1.f / (1.f + expf(-(r * fW[0] + fB[0])));
        const float like   = 1.f / (1.f + expf(-(r * lW[0] + lB[0])));
        *reinterpret_cast<float2*>(&out[b * 2]) = make_float2(finish, like);
    }
}

extern "C" void kernel_launch(void* const* d_in, const int* in_sizes, int n_in,
                              void* d_out, int out_size, void* d_ws, size_t ws_size,
                              hipStream_t stream) {
    const int*   sparse  = (const int*)  d_in[0];
    const float* dense   = (const float*)d_in[1];
    const float* ldW     = (const float*)d_in[2];
    const float* ldB     = (const float*)d_in[3];
    const float* lin_emb = (const float*)d_in[4];
    const float* fm_emb  = (const float*)d_in[5];
    const float* fW      = (const float*)d_in[6];
    const float* fB      = (const float*)d_in[7];
    const float* lW      = (const float*)d_in[8];
    const float* lB      = (const float*)d_in[9];
    float* out = (float*)d_out;

    dim3 grid(B_TOT / 16);   // 1024 blocks, 16 waves/CU
    dim3 block(256);
    fm_mtl_kernel<<<grid, block, 0, stream>>>(
        sparse, dense, ldW, ldB, lin_emb, fm_emb, fW, fB, lW, lB, out);
}